// Round 10
// baseline (120.713 us; speedup 1.0000x reference)
//
#include <hip/hip_runtime.h>
#include <math.h>

#ifndef NSWEEP
#define NSWEEP 4   // 4x4 SPD cyclic Jacobi: rel off-diag ~1e-8 after 4 sweeps
#endif

#define EPSV 1e-8f
#define NM 3        // matrices per thread (78 state floats; needs ~100 VGPRs live)
#define BT 256      // threads per block
#define MPB (NM * BT)

__device__ __forceinline__ float fast_rsqf(float x) {
#if __has_builtin(__builtin_amdgcn_rsqf)
  return __builtin_amdgcn_rsqf(x);
#else
  return rsqrtf(x);
#endif
}
__device__ __forceinline__ float fast_logf(float x) {
#if __has_builtin(__builtin_amdgcn_logf)
  return __builtin_amdgcn_logf(x) * 0.6931471805599453f;  // v_log_f32 is log2
#else
  return logf(x);
#endif
}

// Givens rotation (p,q), short-critical-path form (2 dependent rsq, no sqrt/rcp):
//   h = 1/r, p = |d|/r, q = 2+2p, ri = 1/sqrt(q)
//   c = q*ri/2 ; s = sgn(d)*(2a/r)*ri ; t = 2n*ri^2
// Degenerate d=a=0: max(r2,1e-30) keeps h finite; cndmask p=1 -> c=1,s=0,t=0.
// HW-verified in R5 (absmax identical to R1 reference-form).
#define JROT(APP, AQQ, APQ, AK1P, AK1Q, AK2P, AK2Q,                         \
             VP0, VQ0, VP1, VQ1, VP2, VQ2, VP3, VQ3)                        \
  do {                                                                      \
    float aa_ = APQ;                                                        \
    float d_ = AQQ - APP;                                                   \
    float a2_ = aa_ + aa_;                                                  \
    float r2_ = fmaf(d_, d_, a2_ * a2_);                                    \
    float h_ = fast_rsqf(fmaxf(r2_, 1e-30f));                               \
    float p_ = fabsf(d_) * h_;                                              \
    p_ = (r2_ <= 1e-30f) ? 1.0f : p_;                                       \
    float q_ = fmaf(2.0f, p_, 2.0f);                                        \
    float ri_ = fast_rsqf(q_);                                              \
    float c_ = q_ * (0.5f * ri_);                                           \
    float n_ = __int_as_float(__float_as_int(a2_ * h_) ^                    \
                              (__float_as_int(d_) & 0x80000000));           \
    float s_ = n_ * ri_;                                                    \
    float t_ = (n_ + n_) * (ri_ * ri_);                                     \
    float ta_ = t_ * aa_;                                                   \
    APP = APP - ta_;                                                        \
    AQQ = AQQ + ta_;                                                        \
    APQ = 0.0f;                                                             \
    { float kp_ = AK1P, kq_ = AK1Q;                                         \
      AK1P = fmaf(c_, kp_, -s_ * kq_);                                      \
      AK1Q = fmaf(s_, kp_, c_ * kq_); }                                     \
    { float kp_ = AK2P, kq_ = AK2Q;                                         \
      AK2P = fmaf(c_, kp_, -s_ * kq_);                                      \
      AK2Q = fmaf(s_, kp_, c_ * kq_); }                                     \
    { float p0_ = VP0, q0_ = VQ0;                                           \
      VP0 = fmaf(c_, p0_, -s_ * q0_);                                       \
      VQ0 = fmaf(s_, p0_, c_ * q0_); }                                      \
    { float p0_ = VP1, q0_ = VQ1;                                           \
      VP1 = fmaf(c_, p0_, -s_ * q0_);                                       \
      VQ1 = fmaf(s_, p0_, c_ * q0_); }                                      \
    { float p0_ = VP2, q0_ = VQ2;                                           \
      VP2 = fmaf(c_, p0_, -s_ * q0_);                                       \
      VQ2 = fmaf(s_, p0_, c_ * q0_); }                                      \
    { float p0_ = VP3, q0_ = VQ3;                                           \
      VP3 = fmaf(c_, p0_, -s_ * q0_);                                       \
      VQ3 = fmaf(s_, p0_, c_ * q0_); }                                      \
  } while (0)

// A upper-tri idx: (0,0)=0 (0,1)=1 (0,2)=2 (0,3)=3 (1,1)=4 (1,2)=5 (1,3)=6
// (2,2)=7 (2,3)=8 (3,3)=9.  V[m][i*4+j] = V_ij. Compile-time indices only.
#define ROT_01(m) JROT(A[m][0], A[m][4], A[m][1], A[m][2], A[m][5],         \
                       A[m][3], A[m][6], V[m][0], V[m][1], V[m][4],         \
                       V[m][5], V[m][8], V[m][9], V[m][12], V[m][13])
#define ROT_02(m) JROT(A[m][0], A[m][7], A[m][2], A[m][1], A[m][5],         \
                       A[m][3], A[m][8], V[m][0], V[m][2], V[m][4],         \
                       V[m][6], V[m][8], V[m][10], V[m][12], V[m][14])
#define ROT_03(m) JROT(A[m][0], A[m][9], A[m][3], A[m][1], A[m][6],         \
                       A[m][2], A[m][8], V[m][0], V[m][3], V[m][4],         \
                       V[m][7], V[m][8], V[m][11], V[m][12], V[m][15])
#define ROT_12(m) JROT(A[m][4], A[m][7], A[m][5], A[m][1], A[m][2],         \
                       A[m][6], A[m][8], V[m][1], V[m][2], V[m][5],         \
                       V[m][6], V[m][9], V[m][10], V[m][13], V[m][14])
#define ROT_13(m) JROT(A[m][4], A[m][9], A[m][6], A[m][1], A[m][3],         \
                       A[m][5], A[m][8], V[m][1], V[m][3], V[m][5],         \
                       V[m][7], V[m][9], V[m][11], V[m][13], V[m][15])
#define ROT_23(m) JROT(A[m][7], A[m][9], A[m][8], A[m][2], A[m][3],         \
                       A[m][5], A[m][6], V[m][2], V[m][3], V[m][6],         \
                       V[m][7], V[m][10], V[m][11], V[m][14], V[m][15])

// __launch_bounds__(256, 4): 4 waves/EU guaranteed -> VGPR budget 128, enough
// to keep all 3 rotation chains live (R5 showed default budget=64 serializes).
__global__ __launch_bounds__(256, 4) void TangentSpaceLayer_64141041598486_kernel(
    const float* __restrict__ x, float* __restrict__ out, int B) {
  __shared__ __align__(16) float so[BT * 10];  // 10 KiB, reused NM times
  const int t = threadIdx.x;
  const int base = blockIdx.x * MPB;

  float A[NM][10];
  float V[NM][16];

#pragma unroll
  for (int m = 0; m < NM; ++m) {
    const int idx = min(base + m * BT + t, B - 1);  // clamped tail, discarded
    const float4* p = (const float4*)(x + (size_t)idx * 16);
    float4 r0 = p[0], r1 = p[1], r2 = p[2], r3 = p[3];
    A[m][0] = r0.x + EPSV;
    A[m][1] = 0.5f * (r0.y + r1.x);
    A[m][2] = 0.5f * (r0.z + r2.x);
    A[m][3] = 0.5f * (r0.w + r3.x);
    A[m][4] = r1.y + EPSV;
    A[m][5] = 0.5f * (r1.z + r2.y);
    A[m][6] = 0.5f * (r1.w + r3.y);
    A[m][7] = r2.z + EPSV;
    A[m][8] = 0.5f * (r2.w + r3.z);
    A[m][9] = r3.w + EPSV;
#pragma unroll
    for (int i = 0; i < 16; ++i) V[m][i] = (i % 5 == 0) ? 1.0f : 0.0f;
  }

#pragma unroll 1
  for (int sweep = 0; sweep < NSWEEP; ++sweep) {
    // 3 independent chains interleaved per rotation position (latency hiding)
#pragma unroll
    for (int m = 0; m < NM; ++m) ROT_01(m);
#pragma unroll
    for (int m = 0; m < NM; ++m) ROT_02(m);
#pragma unroll
    for (int m = 0; m < NM; ++m) ROT_03(m);
#pragma unroll
    for (int m = 0; m < NM; ++m) ROT_12(m);
#pragma unroll
    for (int m = 0; m < NM; ++m) ROT_13(m);
#pragma unroll
    for (int m = 0; m < NM; ++m) ROT_23(m);
  }

  // Epilogue per matrix: reconstruct, stage in the SHARED 10 KiB buffer,
  // cooperatively store, then reuse the buffer for the next m.
#pragma unroll
  for (int m = 0; m < NM; ++m) {
    float lw0 = fast_logf(fmaxf(A[m][0], EPSV));
    float lw1 = fast_logf(fmaxf(A[m][4], EPSV));
    float lw2 = fast_logf(fmaxf(A[m][7], EPSV));
    float lw3 = fast_logf(fmaxf(A[m][9], EPSV));

    float w00 = V[m][0] * lw0, w01 = V[m][1] * lw1, w02 = V[m][2] * lw2,
          w03 = V[m][3] * lw3;
    float w10 = V[m][4] * lw0, w11 = V[m][5] * lw1, w12 = V[m][6] * lw2,
          w13 = V[m][7] * lw3;
    float w20 = V[m][8] * lw0, w21 = V[m][9] * lw1, w22 = V[m][10] * lw2,
          w23 = V[m][11] * lw3;
    float w30 = V[m][12] * lw0, w31 = V[m][13] * lw1, w32 = V[m][14] * lw2,
          w33 = V[m][15] * lw3;

    float* sp = so + t * 10;
    sp[0] = fmaf(w00, V[m][0], fmaf(w01, V[m][1], fmaf(w02, V[m][2], w03 * V[m][3])));
    sp[1] = fmaf(w00, V[m][4], fmaf(w01, V[m][5], fmaf(w02, V[m][6], w03 * V[m][7])));
    sp[2] = fmaf(w00, V[m][8], fmaf(w01, V[m][9], fmaf(w02, V[m][10], w03 * V[m][11])));
    sp[3] = fmaf(w00, V[m][12], fmaf(w01, V[m][13], fmaf(w02, V[m][14], w03 * V[m][15])));
    sp[4] = fmaf(w10, V[m][4], fmaf(w11, V[m][5], fmaf(w12, V[m][6], w13 * V[m][7])));
    sp[5] = fmaf(w10, V[m][8], fmaf(w11, V[m][9], fmaf(w12, V[m][10], w13 * V[m][11])));
    sp[6] = fmaf(w10, V[m][12], fmaf(w11, V[m][13], fmaf(w12, V[m][14], w13 * V[m][15])));
    sp[7] = fmaf(w20, V[m][8], fmaf(w21, V[m][9], fmaf(w22, V[m][10], w23 * V[m][11])));
    sp[8] = fmaf(w20, V[m][12], fmaf(w21, V[m][13], fmaf(w22, V[m][14], w23 * V[m][15])));
    sp[9] = fmaf(w30, V[m][12], fmaf(w31, V[m][13], fmaf(w32, V[m][14], w33 * V[m][15])));

    __syncthreads();

    const int mbase = base + m * BT;
    const int valid = min(BT, B - mbase);   // may be <=0 for dead tail rounds
    const int nf = valid * 10;
    const int n4 = nf >> 2;
    float* obase = out + (size_t)mbase * 10;
    const float4* s4 = (const float4*)so;
    float4* o4 = (float4*)obase;
    for (int i = t; i < n4; i += BT) o4[i] = s4[i];
    for (int i = n4 * 4 + t; i < nf; i += BT) obase[i] = so[i];

    __syncthreads();  // buffer reuse guard for next m
  }
}

extern "C" void kernel_launch(void* const* d_in, const int* in_sizes, int n_in,
                              void* d_out, int out_size, void* d_ws, size_t ws_size,
                              hipStream_t stream) {
  const float* x = (const float*)d_in[0];
  float* out = (float*)d_out;
  const int B = in_sizes[0] / 16;
  const int blocks = (B + MPB - 1) / MPB;
  hipLaunchKernelGGL(TangentSpaceLayer_64141041598486_kernel, dim3(blocks),
                     dim3(BT), 0, stream, x, out, B);
}

// Round 11
// 111.914 us; speedup vs baseline: 1.0786x; 1.0786x over previous
//
#include <hip/hip_runtime.h>
#include <math.h>

#ifndef NSWEEP
#define NSWEEP 4   // 4x4 SPD cyclic Jacobi: rel off-diag ~1e-8 after 4 sweeps
#endif

#define EPSV 1e-8f
#define BT 256       // threads per block
#define MPB (2 * BT) // 2 matrices per thread, SoA-paired

__device__ __forceinline__ float fast_rsqf(float x) {
#if __has_builtin(__builtin_amdgcn_rsqf)
  return __builtin_amdgcn_rsqf(x);
#else
  return rsqrtf(x);
#endif
}
__device__ __forceinline__ float fast_logf(float x) {
#if __has_builtin(__builtin_amdgcn_logf)
  return __builtin_amdgcn_logf(x) * 0.6931471805599453f;  // v_log_f32 is log2
#else
  return logf(x);
#endif
}

// f2 = two independent matrices' scalars, forced instruction-pairing.
// Peak pressure ~= serial NM=2 (state live either way), so the scheduler
// has no pressure reason to de-interleave (R5/R10 showed it serializes
// an NM-loop to save temps at its 64-VGPR occupancy target).
struct f2 { float x, y; };
__device__ __forceinline__ f2 F2(float a, float b) { f2 r; r.x = a; r.y = b; return r; }
__device__ __forceinline__ f2 f2add(f2 a, f2 b) { return F2(a.x + b.x, a.y + b.y); }
__device__ __forceinline__ f2 f2sub(f2 a, f2 b) { return F2(a.x - b.x, a.y - b.y); }
__device__ __forceinline__ f2 f2mul(f2 a, f2 b) { return F2(a.x * b.x, a.y * b.y); }
__device__ __forceinline__ f2 f2muls(f2 a, float s) { return F2(a.x * s, a.y * s); }
__device__ __forceinline__ f2 f2fma(f2 a, f2 b, f2 c) {
  return F2(fmaf(a.x, b.x, c.x), fmaf(a.y, b.y, c.y));
}
__device__ __forceinline__ f2 f2rsq(f2 a) { return F2(fast_rsqf(a.x), fast_rsqf(a.y)); }
__device__ __forceinline__ f2 f2abs(f2 a) { return F2(fabsf(a.x), fabsf(a.y)); }
__device__ __forceinline__ f2 f2maxs(f2 a, float s) { return F2(fmaxf(a.x, s), fmaxf(a.y, s)); }
__device__ __forceinline__ f2 f2log(f2 a) { return F2(fast_logf(fmaxf(a.x, EPSV)), fast_logf(fmaxf(a.y, EPSV))); }
__device__ __forceinline__ f2 f2neg(f2 a) { return F2(-a.x, -a.y); }
__device__ __forceinline__ f2 f2sgnx(f2 mag, f2 sgn) {  // mag ^ signbit(sgn)
  return F2(__int_as_float(__float_as_int(mag.x) ^ (__float_as_int(sgn.x) & 0x80000000)),
            __int_as_float(__float_as_int(mag.y) ^ (__float_as_int(sgn.y) & 0x80000000)));
}
__device__ __forceinline__ f2 f2selp(f2 r2, f2 p) {  // (r2<=1e-30) ? 1 : p
  return F2(r2.x <= 1e-30f ? 1.0f : p.x, r2.y <= 1e-30f ? 1.0f : p.y);
}

// 2x2 rotation of the (P,Q) pair by (c_, s_, ns_) from enclosing JROT scope.
#define ROTP_(P, Q)                                   \
  { f2 p0_ = P, q0_ = Q;                              \
    P = f2fma(c_, p0_, f2mul(ns_, q0_));              \
    Q = f2fma(s_, p0_, f2mul(c_, q0_)); }

// Givens rotation (p,q), short-critical-path form (HW-verified R5/R10:
// absmax identical to reference-form). Componentwise over the f2 pair.
#define JROT(APP, AQQ, APQ, AK1P, AK1Q, AK2P, AK2Q,                         \
             VP0, VQ0, VP1, VQ1, VP2, VQ2, VP3, VQ3)                        \
  do {                                                                      \
    f2 aa_ = APQ;                                                           \
    f2 d_ = f2sub(AQQ, APP);                                                \
    f2 a2_ = f2add(aa_, aa_);                                               \
    f2 r2_ = f2fma(d_, d_, f2mul(a2_, a2_));                                \
    f2 h_ = f2rsq(f2maxs(r2_, 1e-30f));                                     \
    f2 p_ = f2selp(r2_, f2mul(f2abs(d_), h_));                              \
    f2 q_ = F2(fmaf(2.0f, p_.x, 2.0f), fmaf(2.0f, p_.y, 2.0f));             \
    f2 ri_ = f2rsq(q_);                                                     \
    f2 c_ = f2mul(q_, f2muls(ri_, 0.5f));                                   \
    f2 n_ = f2sgnx(f2mul(a2_, h_), d_);                                     \
    f2 s_ = f2mul(n_, ri_);                                                 \
    f2 ns_ = f2neg(s_);                                                     \
    f2 t_ = f2mul(f2add(n_, n_), f2mul(ri_, ri_));                          \
    f2 ta_ = f2mul(t_, aa_);                                                \
    APP = f2sub(APP, ta_);                                                  \
    AQQ = f2add(AQQ, ta_);                                                  \
    APQ = F2(0.0f, 0.0f);                                                   \
    ROTP_(AK1P, AK1Q)                                                       \
    ROTP_(AK2P, AK2Q)                                                       \
    ROTP_(VP0, VQ0)                                                         \
    ROTP_(VP1, VQ1)                                                         \
    ROTP_(VP2, VQ2)                                                         \
    ROTP_(VP3, VQ3)                                                         \
  } while (0)

// A upper-tri idx: (0,0)=0 (0,1)=1 (0,2)=2 (0,3)=3 (1,1)=4 (1,2)=5 (1,3)=6
// (2,2)=7 (2,3)=8 (3,3)=9.  V[i*4+j] = V_ij. Compile-time indices only.
#define ROT_01 JROT(A[0], A[4], A[1], A[2], A[5], A[3], A[6],               \
                    V[0], V[1], V[4], V[5], V[8], V[9], V[12], V[13])
#define ROT_02 JROT(A[0], A[7], A[2], A[1], A[5], A[3], A[8],               \
                    V[0], V[2], V[4], V[6], V[8], V[10], V[12], V[14])
#define ROT_03 JROT(A[0], A[9], A[3], A[1], A[6], A[2], A[8],               \
                    V[0], V[3], V[4], V[7], V[8], V[11], V[12], V[15])
#define ROT_12 JROT(A[4], A[7], A[5], A[1], A[2], A[6], A[8],               \
                    V[1], V[2], V[5], V[6], V[9], V[10], V[13], V[14])
#define ROT_13 JROT(A[4], A[9], A[6], A[1], A[3], A[5], A[8],               \
                    V[1], V[3], V[5], V[7], V[9], V[11], V[13], V[15])
#define ROT_23 JROT(A[7], A[9], A[8], A[2], A[3], A[5], A[6],               \
                    V[2], V[3], V[6], V[7], V[10], V[11], V[14], V[15])

__global__ __launch_bounds__(256, 4) void TangentSpaceLayer_64141041598486_kernel(
    const float* __restrict__ x, float* __restrict__ out, int B) {
  __shared__ __align__(16) float so[BT * 10];  // 10 KiB, reused for 2 halves
  const int t = threadIdx.x;
  const int base = blockIdx.x * MPB;
  const int i0 = min(base + t, B - 1);        // x-lane matrix
  const int i1 = min(base + BT + t, B - 1);   // y-lane matrix (clamped tail)

  const float4* p0 = (const float4*)(x + (size_t)i0 * 16);
  const float4* p1 = (const float4*)(x + (size_t)i1 * 16);
  float4 a0 = p0[0], a1 = p0[1], a2 = p0[2], a3 = p0[3];
  float4 b0 = p1[0], b1 = p1[1], b2 = p1[2], b3 = p1[3];

  f2 A[10], V[16];
  // symmetrize + EPS*I, both matrices packed per component
  A[0] = F2(a0.x + EPSV, b0.x + EPSV);
  A[1] = F2(0.5f * (a0.y + a1.x), 0.5f * (b0.y + b1.x));
  A[2] = F2(0.5f * (a0.z + a2.x), 0.5f * (b0.z + b2.x));
  A[3] = F2(0.5f * (a0.w + a3.x), 0.5f * (b0.w + b3.x));
  A[4] = F2(a1.y + EPSV, b1.y + EPSV);
  A[5] = F2(0.5f * (a1.z + a2.y), 0.5f * (b1.z + b2.y));
  A[6] = F2(0.5f * (a1.w + a3.y), 0.5f * (b1.w + b3.y));
  A[7] = F2(a2.z + EPSV, b2.z + EPSV);
  A[8] = F2(0.5f * (a2.w + a3.z), 0.5f * (b2.w + b3.z));
  A[9] = F2(a3.w + EPSV, b3.w + EPSV);
#pragma unroll
  for (int i = 0; i < 16; ++i) V[i] = F2((i % 5 == 0) ? 1.0f : 0.0f,
                                         (i % 5 == 0) ? 1.0f : 0.0f);

#pragma unroll 1
  for (int sweep = 0; sweep < NSWEEP; ++sweep) {
    ROT_01; ROT_02; ROT_03; ROT_12; ROT_13; ROT_23;
  }

  // epilogue: logm reconstruction, both matrices per component
  f2 lw0 = f2log(A[0]);
  f2 lw1 = f2log(A[4]);
  f2 lw2 = f2log(A[7]);
  f2 lw3 = f2log(A[9]);

  f2 w00 = f2mul(V[0], lw0),  w01 = f2mul(V[1], lw1),
     w02 = f2mul(V[2], lw2),  w03 = f2mul(V[3], lw3);
  f2 w10 = f2mul(V[4], lw0),  w11 = f2mul(V[5], lw1),
     w12 = f2mul(V[6], lw2),  w13 = f2mul(V[7], lw3);
  f2 w20 = f2mul(V[8], lw0),  w21 = f2mul(V[9], lw1),
     w22 = f2mul(V[10], lw2), w23 = f2mul(V[11], lw3);
  f2 w30 = f2mul(V[12], lw0), w31 = f2mul(V[13], lw1),
     w32 = f2mul(V[14], lw2), w33 = f2mul(V[15], lw3);

  f2 o[10];
  o[0] = f2fma(w00, V[0],  f2fma(w01, V[1],  f2fma(w02, V[2],  f2mul(w03, V[3]))));
  o[1] = f2fma(w00, V[4],  f2fma(w01, V[5],  f2fma(w02, V[6],  f2mul(w03, V[7]))));
  o[2] = f2fma(w00, V[8],  f2fma(w01, V[9],  f2fma(w02, V[10], f2mul(w03, V[11]))));
  o[3] = f2fma(w00, V[12], f2fma(w01, V[13], f2fma(w02, V[14], f2mul(w03, V[15]))));
  o[4] = f2fma(w10, V[4],  f2fma(w11, V[5],  f2fma(w12, V[6],  f2mul(w13, V[7]))));
  o[5] = f2fma(w10, V[8],  f2fma(w11, V[9],  f2fma(w12, V[10], f2mul(w13, V[11]))));
  o[6] = f2fma(w10, V[12], f2fma(w11, V[13], f2fma(w12, V[14], f2mul(w13, V[15]))));
  o[7] = f2fma(w20, V[8],  f2fma(w21, V[9],  f2fma(w22, V[10], f2mul(w23, V[11]))));
  o[8] = f2fma(w20, V[12], f2fma(w21, V[13], f2fma(w22, V[14], f2mul(w23, V[15]))));
  o[9] = f2fma(w30, V[12], f2fma(w31, V[13], f2fma(w32, V[14], f2mul(w33, V[15]))));

  // two sync-guarded store rounds through the shared 10 KiB buffer
#pragma unroll 1
  for (int half = 0; half < 2; ++half) {
    float* sp = so + t * 10;
#pragma unroll
    for (int i = 0; i < 10; ++i) sp[i] = half ? o[i].y : o[i].x;

    __syncthreads();

    const int mbase = base + half * BT;
    const int valid = min(BT, B - mbase);
    const int nf = valid * 10;
    const int n4 = nf >> 2;
    float* obase = out + (size_t)mbase * 10;
    const float4* s4 = (const float4*)so;
    float4* o4 = (float4*)obase;
    for (int i = t; i < n4; i += BT) o4[i] = s4[i];
    for (int i = n4 * 4 + t; i < nf; i += BT) obase[i] = so[i];

    __syncthreads();  // buffer reuse guard
  }
}

extern "C" void kernel_launch(void* const* d_in, const int* in_sizes, int n_in,
                              void* d_out, int out_size, void* d_ws, size_t ws_size,
                              hipStream_t stream) {
  const float* x = (const float*)d_in[0];
  float* out = (float*)d_out;
  const int B = in_sizes[0] / 16;
  const int blocks = (B + MPB - 1) / MPB;
  hipLaunchKernelGGL(TangentSpaceLayer_64141041598486_kernel, dim3(blocks),
                     dim3(BT), 0, stream, x, out, B);
}